// Round 6
// baseline (684.768 us; speedup 1.0000x reference)
//
#include <hip/hip_runtime.h>
#include <math.h>

#define NE   1024
#define ED   256
#define NT   131072
#define SLOTS 24

typedef __attribute__((ext_vector_type(8))) short short8;
typedef __attribute__((ext_vector_type(4))) float f32x4;

__device__ inline unsigned short f2bf(float f) {
    unsigned u = __float_as_uint(f);
    unsigned r = (u + 0x7FFFu + ((u >> 16) & 1u)) >> 16;   // RNE
    return (unsigned short)r;
}

__device__ inline void gl_lds16(const void* g, void* l) {
    __builtin_amdgcn_global_load_lds(
        (const __attribute__((address_space(1))) unsigned int*)g,
        (__attribute__((address_space(3))) unsigned int*)l, 16, 0, 0);
}

// packed candidate: (q(s~) << 16) | code ; q monotone in s~ so u32-min is
// lexicographic (s~, code)-min. q = floor((s + 1024) * 16), clamped.
__device__ inline unsigned pack_cand(float s, int code) {
    float qf = (s + 1024.f) * 16.f;
    int q = (int)qf;
    q = q < 0 ? 0 : (q > 65535 ? 65535 : q);
    return ((unsigned)q << 16) | (unsigned)code;
}

// ---------------------------------------------------------------------------
// ws layout:
//   0        wnorm  f32[1024]
//   4096     counts int[1024]
//   8192     wmax   f32[1]
//   8448     wb     bf16[1024*256]    (512 KB)
//   532736   cnt    u32[131072]       (512 KB)
//   1057024  cand   u32[131072*24]    (12.6 MB)   need = 13639936
// ---------------------------------------------------------------------------

__global__ __launch_bounds__(256) void vq_prep(const float* __restrict__ w,
                                               float* __restrict__ wnorm,
                                               int* __restrict__ counts,
                                               unsigned short* __restrict__ wb) {
    int c = blockIdx.x * 256 + threadIdx.x;
    if (c < NE) {
        const float4* row = reinterpret_cast<const float4*>(w + (size_t)c * ED);
        ushort4* wbr = reinterpret_cast<ushort4*>(wb + (size_t)c * ED);
        float s = 0.f;
#pragma unroll 8
        for (int i = 0; i < ED / 4; ++i) {
            float4 v = row[i];
            s += v.x * v.x + v.y * v.y + v.z * v.z + v.w * v.w;
            ushort4 o;
            o.x = f2bf(v.x); o.y = f2bf(v.y); o.z = f2bf(v.z); o.w = f2bf(v.w);
            wbr[i] = o;
        }
        wnorm[c] = s;
        counts[c] = 0;
    }
}

__global__ __launch_bounds__(1024) void vq_wmax(const float* __restrict__ wnorm,
                                                float* __restrict__ wmax) {
    __shared__ float red[16];
    int tid = threadIdx.x;
    float v = wnorm[tid];
#pragma unroll
    for (int m = 32; m >= 1; m >>= 1) v = fmaxf(v, __shfl_xor(v, m, 64));
    if ((tid & 63) == 0) red[tid >> 6] = v;
    __syncthreads();
    if (tid == 0) {
        float m = red[0];
#pragma unroll
        for (int i = 1; i < 16; ++i) m = fmaxf(m, red[i]);
        wmax[0] = sqrtf(m);
    }
}

// W-stationary score kernel: 512 blocks x 512 threads (8 waves x 32 tokens).
// Per block: 4 quarters of 256 codes; each quarter staged once into 128 KB
// LDS, then every wave sweeps it independently (NO per-tile barriers, NO
// atomics). Candidate positions via 16-lane-group ballot prefix + register
// counters; plain stores.
__global__ __launch_bounds__(512, 2) void vq_score2(const float* __restrict__ z,
                                                    const unsigned short* __restrict__ wb,
                                                    const float* __restrict__ wnorm,
                                                    const float* __restrict__ wmaxp,
                                                    unsigned* __restrict__ cnt,
                                                    unsigned* __restrict__ cand) {
    __shared__ __align__(16) unsigned short wlds[65536];   // 128 KB
    __shared__ float wn_lds[NE];                           // 4 KB
    __shared__ float thr_lds[8][32];                       // 1 KB

    const int tid  = threadIdx.x;
    const int lane = tid & 63;
    const int wv_  = tid >> 6;          // 0..7
    const int l15  = lane & 15;
    const int l4   = lane >> 4;
    const int row0 = blockIdx.x * 256 + wv_ * 32;

    // wnorm -> LDS (512 threads x float2)
    reinterpret_cast<float2*>(wn_lds)[tid] = reinterpret_cast<const float2*>(wnorm)[tid];

    // ---- A: z fp32 -> bf16 fragments (row=l15, k=kg*32 + l4*8 + i) ----
    short8 a[2][8];
    float zn2[2];
#pragma unroll
    for (int mi = 0; mi < 2; ++mi) {
        const float* zr = z + (size_t)(row0 + mi * 16 + l15) * ED;
        float s = 0.f;
#pragma unroll
        for (int kg = 0; kg < 8; ++kg) {
            int k0 = kg * 32 + l4 * 8;
            float4 p = *reinterpret_cast<const float4*>(zr + k0);
            float4 q = *reinterpret_cast<const float4*>(zr + k0 + 4);
            s += p.x * p.x + p.y * p.y + p.z * p.z + p.w * p.w
               + q.x * q.x + q.y * q.y + q.z * q.z + q.w * q.w;
            short8 t;
            t[0] = (short)f2bf(p.x); t[1] = (short)f2bf(p.y);
            t[2] = (short)f2bf(p.z); t[3] = (short)f2bf(p.w);
            t[4] = (short)f2bf(q.x); t[5] = (short)f2bf(q.y);
            t[6] = (short)f2bf(q.z); t[7] = (short)f2bf(q.w);
            a[mi][kg] = t;
        }
        zn2[mi] = s;
    }
#pragma unroll
    for (int mi = 0; mi < 2; ++mi) {
        zn2[mi] += __shfl_xor(zn2[mi], 16, 64);
        zn2[mi] += __shfl_xor(zn2[mi], 32, 64);
    }
    float wmax = wmaxp[0];
#pragma unroll
    for (int mi = 0; mi < 2; ++mi)
        thr_lds[wv_][mi * 16 + l15] = 0.0313f * sqrtf(zn2[mi]) * wmax + 0.05f;

    // ---- stage quarter 0: 128 frags of 1 KB; wave wv_ stages s = wv_*16+p ----
#pragma unroll
    for (int p = 0; p < 16; ++p) {
        int s  = wv_ * 16 + p;
        int nj = s >> 3, kg = s & 7;
        int j  = nj * 16 + l15;                          // q = 0
        gl_lds16(wb + (size_t)j * ED + kg * 32 + l4 * 8, &wlds[s * 512]);
    }
    asm volatile("s_waitcnt vmcnt(0) lgkmcnt(0)" ::: "memory");
    __builtin_amdgcn_s_barrier();

    float thrR[2][4];
#pragma unroll
    for (int mi = 0; mi < 2; ++mi)
#pragma unroll
        for (int r = 0; r < 4; ++r)
            thrR[mi][r] = thr_lds[wv_][mi * 16 + l4 * 4 + r];

    float mn[2][4], pmin[2][4];
    int cnt_reg[8];
#pragma unroll
    for (int mi = 0; mi < 2; ++mi)
#pragma unroll
        for (int r = 0; r < 4; ++r) {
            mn[mi][r] = 3.4e38f; pmin[mi][r] = 3.4e38f;
            cnt_reg[mi * 4 + r] = 0;
        }

    for (int q = 0; q < 4; ++q) {
        const int c0 = q * 256;

        for (int nj = 0; nj < 16; ++nj) {
            f32x4 acc[2];
            acc[0] = {0.f, 0.f, 0.f, 0.f};
            acc[1] = {0.f, 0.f, 0.f, 0.f};
#pragma unroll
            for (int kg = 0; kg < 8; ++kg) {
                short8 wf = *reinterpret_cast<const short8*>(
                    &wlds[(nj * 8 + kg) * 512 + lane * 8]);
                acc[0] = __builtin_amdgcn_mfma_f32_16x16x32_bf16(a[0][kg], wf, acc[0], 0, 0, 0);
                acc[1] = __builtin_amdgcn_mfma_f32_16x16x32_bf16(a[1][kg], wf, acc[1], 0, 0, 0);
            }

            float wnv = wn_lds[c0 + nj * 16 + l15];
            int kb = 0;
#pragma unroll
            for (int mi = 0; mi < 2; ++mi)
#pragma unroll
                for (int r = 0; r < 4; ++r) {
                    float s = fmaf(-2.f, acc[mi][r], wnv);
                    acc[mi][r] = s;
                    pmin[mi][r] = fminf(pmin[mi][r], s);
                }

            // fold per-thread running min into mn: every nj for the first 4
            // tiles (prevents early append flood), then every other tile.
            const int ti = q * 16 + nj;
            if (ti < 4 || (ti & 1)) {
#pragma unroll
                for (int mi = 0; mi < 2; ++mi)
#pragma unroll
                    for (int r = 0; r < 4; ++r) {
                        float v = pmin[mi][r];
#pragma unroll
                        for (int m = 1; m < 16; m <<= 1)
                            v = fminf(v, __shfl_xor(v, m, 64));
                        mn[mi][r] = v;
                    }
            }

#pragma unroll
            for (int mi = 0; mi < 2; ++mi)
#pragma unroll
                for (int r = 0; r < 4; ++r)
                    if (acc[mi][r] <= mn[mi][r] + thrR[mi][r]) kb |= 1 << (mi * 4 + r);

            if (__any(kb != 0)) {
                const int code = c0 + nj * 16 + l15;
#pragma unroll
                for (int mi = 0; mi < 2; ++mi)
#pragma unroll
                    for (int r = 0; r < 4; ++r) {
                        const int idx = mi * 4 + r;
                        unsigned long long b = __ballot((kb >> idx) & 1);
                        unsigned gm = (unsigned)((b >> (l4 * 16)) & 0xFFFFull);
                        if (gm) {
                            if ((kb >> idx) & 1) {
                                int prefix = __popc(gm & ((1u << l15) - 1u));
                                int pos = cnt_reg[idx] + prefix;
                                if (pos < SLOTS) {
                                    int tok = row0 + mi * 16 + l4 * 4 + r;
                                    cand[(size_t)tok * SLOTS + pos] =
                                        pack_cand(acc[mi][r], code);
                                }
                            }
                            cnt_reg[idx] += __popc(gm);
                        }
                    }
            }
        }

        // re-stage next quarter (single buffer: all waves must be done reading)
        if (q < 3) {
            asm volatile("s_waitcnt lgkmcnt(0)" ::: "memory");
            __builtin_amdgcn_s_barrier();
#pragma unroll
            for (int p = 0; p < 16; ++p) {
                int s  = wv_ * 16 + p;
                int nj = s >> 3, kg = s & 7;
                int j  = (q + 1) * 256 + nj * 16 + l15;
                gl_lds16(wb + (size_t)j * ED + kg * 32 + l4 * 8, &wlds[s * 512]);
            }
            asm volatile("s_waitcnt vmcnt(0) lgkmcnt(0)" ::: "memory");
            __builtin_amdgcn_s_barrier();
        }
    }

    // final per-token candidate counts (one lane per token group)
    if (l15 == 0) {
#pragma unroll
        for (int idx = 0; idx < 8; ++idx) {
            int tok = row0 + (idx >> 2) * 16 + l4 * 4 + (idx & 3);
            cnt[tok] = (unsigned)cnt_reg[idx];
        }
    }
}

// Exact fp32 refine: wave-parallel prune on packed (q,code), then exact
// evaluation of survivors; fused gather of z_q and counts histogram.
__global__ __launch_bounds__(256) void vq_refine(const float* __restrict__ z,
                                                 const float* __restrict__ w,
                                                 const float* __restrict__ wnorm,
                                                 const float* __restrict__ wmaxp,
                                                 const unsigned* __restrict__ cnt,
                                                 const unsigned* __restrict__ cand,
                                                 int* __restrict__ counts,
                                                 float* __restrict__ out) {
    const int lane = threadIdx.x & 63;
    const int t = blockIdx.x * 4 + (threadIdx.x >> 6);
    float4 zv = reinterpret_cast<const float4*>(z + (size_t)t * ED)[lane];
    unsigned n = cnt[t];
    float bs = 3.4e38f;
    int bj = NE;

    if (n >= 1u && n <= (unsigned)SLOTS) {
        unsigned pk = 0xFFFFFFFFu;
        if (lane < (int)n) pk = cand[(size_t)t * SLOTS + lane];
        unsigned pmin = pk;
#pragma unroll
        for (int m = 1; m < 64; m <<= 1) {
            unsigned o = __shfl_xor(pmin, m, 64);
            pmin = o < pmin ? o : pmin;
        }
        // same thr formula as score; margin covers 2 quantization steps
        float zn = zv.x * zv.x + zv.y * zv.y + zv.z * zv.z + zv.w * zv.w;
#pragma unroll
        for (int m = 1; m < 64; m <<= 1) zn += __shfl_xor(zn, m, 64);
        float thr = 0.0313f * sqrtf(zn) * wmaxp[0] + 0.05f;
        unsigned margin = (unsigned)(16.f * thr) + 2u;
        unsigned qmin = pmin >> 16;
        bool keep = (lane < (int)n) && ((pk >> 16) <= qmin + margin);
        unsigned long long mask = __ballot(keep);
        while (mask) {
            int c = __ffsll(mask) - 1;
            mask &= mask - 1;
            int j = (int)(__shfl(pk, c, 64) & 0xFFFFu);
            float4 wv = reinterpret_cast<const float4*>(w + (size_t)j * ED)[lane];
            float d = fmaf(zv.x, wv.x, fmaf(zv.y, wv.y, fmaf(zv.z, wv.z, zv.w * wv.w)));
#pragma unroll
            for (int m = 1; m < 64; m <<= 1) d += __shfl_xor(d, m, 64);
            float s = fmaf(-2.f, d, wnorm[j]);
            if (s < bs || (s == bs && j < bj)) { bs = s; bj = j; }
        }
    } else {
        // overflow (or impossible empty): exact scan of all codes
        for (int j = 0; j < NE; ++j) {
            float4 wv = reinterpret_cast<const float4*>(w + (size_t)j * ED)[lane];
            float d = fmaf(zv.x, wv.x, fmaf(zv.y, wv.y, fmaf(zv.z, wv.z, zv.w * wv.w)));
#pragma unroll
            for (int m = 1; m < 64; m <<= 1) d += __shfl_xor(d, m, 64);
            float s = fmaf(-2.f, d, wnorm[j]);
            if (s < bs || (s == bs && j < bj)) { bs = s; bj = j; }
        }
    }
    float4 bw = reinterpret_cast<const float4*>(w + (size_t)bj * ED)[lane];
    reinterpret_cast<float4*>(out + (size_t)t * ED)[lane] = bw;
    if (lane == 0) atomicAdd(&counts[bj], 1);
}

__global__ __launch_bounds__(1024) void vq_pplx(const int* __restrict__ counts,
                                                float* __restrict__ out) {
    __shared__ float red[16];
    int tid = threadIdx.x;
    float e = (float)counts[tid] * (1.0f / (float)NT);
    float t = -e * logf(e + 1e-10f);
#pragma unroll
    for (int m = 32; m >= 1; m >>= 1) t += __shfl_down(t, m, 64);
    if ((tid & 63) == 0) red[tid >> 6] = t;
    __syncthreads();
    if (tid < 16) {
        float s = red[tid];
#pragma unroll
        for (int m = 8; m >= 1; m >>= 1) s += __shfl_down(s, m, 16);
        if (tid == 0) out[(size_t)NT * ED] = expf(s);
    }
}

// ======================= fallback (round-1, fp32 VALU) =======================
#define TM 64
#define TN 64
#define KC 64

__global__ __launch_bounds__(256) void vq_prep0(const float* __restrict__ w,
                                                float* __restrict__ wnorm,
                                                int* __restrict__ counts) {
    int c = blockIdx.x * blockDim.x + threadIdx.x;
    if (c < NE) {
        const float4* row = reinterpret_cast<const float4*>(w + (size_t)c * ED);
        float s = 0.f;
#pragma unroll 8
        for (int i = 0; i < ED / 4; ++i) {
            float4 v = row[i];
            s += v.x * v.x + v.y * v.y + v.z * v.z + v.w * v.w;
        }
        wnorm[c] = s;
        counts[c] = 0;
    }
}

__global__ __launch_bounds__(256) void vq_argmin0(const float* __restrict__ z,
                                                  const float* __restrict__ w,
                                                  const float* __restrict__ wnorm,
                                                  int* __restrict__ idx_out,
                                                  int* __restrict__ counts) {
    __shared__ float zs[ED][TM];
    __shared__ float wsh[KC][TN];
    const int tid  = threadIdx.x;
    const int row0 = blockIdx.x * TM;
    const int cg   = tid & 15;
    const int tg   = tid >> 4;
#pragma unroll
    for (int p = 0; p < 16; ++p) {
        int f = p * 256 + tid;
        int k = f >> 4;
        int g = f & 15;
        float4 v;
        v.x = z[(size_t)(row0 + g * 4 + 0) * ED + k];
        v.y = z[(size_t)(row0 + g * 4 + 1) * ED + k];
        v.z = z[(size_t)(row0 + g * 4 + 2) * ED + k];
        v.w = z[(size_t)(row0 + g * 4 + 3) * ED + k];
        *reinterpret_cast<float4*>(&zs[k][g * 4]) = v;
    }
    float best[4];
    int   bidx[4];
#pragma unroll
    for (int i = 0; i < 4; ++i) { best[i] = 3.4e38f; bidx[i] = 0; }
    for (int ct = 0; ct < NE / TN; ++ct) {
        const int c0 = ct * TN;
        float acc[4][4];
#pragma unroll
        for (int i = 0; i < 4; ++i)
#pragma unroll
            for (int j = 0; j < 4; ++j) acc[i][j] = 0.f;
        for (int kc = 0; kc < ED / KC; ++kc) {
            __syncthreads();
#pragma unroll
            for (int p = 0; p < 4; ++p) {
                int f = p * 256 + tid;
                int k = f >> 4;
                int g = f & 15;
                float4 v;
                v.x = w[(size_t)(c0 + g * 4 + 0) * ED + kc * KC + k];
                v.y = w[(size_t)(c0 + g * 4 + 1) * ED + kc * KC + k];
                v.z = w[(size_t)(c0 + g * 4 + 2) * ED + kc * KC + k];
                v.w = w[(size_t)(c0 + g * 4 + 3) * ED + kc * KC + k];
                *reinterpret_cast<float4*>(&wsh[k][g * 4]) = v;
            }
            __syncthreads();
#pragma unroll 8
            for (int k = 0; k < KC; ++k) {
                float4 zv = *reinterpret_cast<const float4*>(&zs[kc * KC + k][tg * 4]);
                float4 wv = *reinterpret_cast<const float4*>(&wsh[k][cg * 4]);
                float zr[4] = { zv.x, zv.y, zv.z, zv.w };
                float wr[4] = { wv.x, wv.y, wv.z, wv.w };
#pragma unroll
                for (int i = 0; i < 4; ++i)
#pragma unroll
                    for (int j = 0; j < 4; ++j)
                        acc[i][j] = fmaf(zr[i], wr[j], acc[i][j]);
            }
        }
#pragma unroll
        for (int j = 0; j < 4; ++j) {
            int c = c0 + cg * 4 + j;
            float wn = wnorm[c];
#pragma unroll
            for (int i = 0; i < 4; ++i) {
                float s = fmaf(-2.f, acc[i][j], wn);
                if (s < best[i]) { best[i] = s; bidx[i] = c; }
            }
        }
    }
#pragma unroll
    for (int m = 1; m < 16; m <<= 1) {
#pragma unroll
        for (int i = 0; i < 4; ++i) {
            float ov = __shfl_xor(best[i], m, 64);
            int   oi = __shfl_xor(bidx[i], m, 64);
            if (ov < best[i] || (ov == best[i] && oi < bidx[i])) {
                best[i] = ov; bidx[i] = oi;
            }
        }
    }
    if (cg == 0) {
#pragma unroll
        for (int i = 0; i < 4; ++i) {
            int t = row0 + tg * 4 + i;
            idx_out[t] = bidx[i];
            atomicAdd(&counts[bidx[i]], 1);
        }
    }
}

__global__ __launch_bounds__(256) void vq_gather0(const float* __restrict__ w,
                                                  const int* __restrict__ idx,
                                                  float* __restrict__ out) {
    int tid = threadIdx.x;
    int t   = blockIdx.x * 4 + (tid >> 6);
    int c4  = tid & 63;
    int id  = idx[t];
    float4 v = reinterpret_cast<const float4*>(w + (size_t)id * ED)[c4];
    reinterpret_cast<float4*>(out + (size_t)t * ED)[c4] = v;
}
// ============================================================================

extern "C" void kernel_launch(void* const* d_in, const int* in_sizes, int n_in,
                              void* d_out, int out_size, void* d_ws, size_t ws_size,
                              hipStream_t stream) {
    const float* z = (const float*)d_in[0];
    const float* w = (const float*)d_in[1];
    float* out = (float*)d_out;
    char* ws = (char*)d_ws;

    float*          wnorm  = (float*)ws;
    int*            counts = (int*)(ws + 4096);
    float*          wmax   = (float*)(ws + 8192);
    unsigned short* wb     = (unsigned short*)(ws + 8448);
    unsigned*       cnt    = (unsigned*)(ws + 532736);
    unsigned*       cand   = (unsigned*)(ws + 1057024);
    const size_t need = 1057024 + (size_t)NT * SLOTS * 4;

    if (ws_size >= need) {
        vq_prep<<<4, 256, 0, stream>>>(w, wnorm, counts, wb);
        vq_wmax<<<1, 1024, 0, stream>>>(wnorm, wmax);
        vq_score2<<<NT / 256, 512, 0, stream>>>(z, wb, wnorm, wmax, cnt, cand);
        vq_refine<<<NT / 4, 256, 0, stream>>>(z, w, wnorm, wmax, cnt, cand, counts, out);
        vq_pplx<<<1, 1024, 0, stream>>>(counts, out);
    } else {
        int* idxw = (int*)(ws + 8192);
        vq_prep0<<<(NE + 255) / 256, 256, 0, stream>>>(w, wnorm, counts);
        vq_argmin0<<<NT / TM, 256, 0, stream>>>(z, w, wnorm, idxw, counts);
        vq_gather0<<<NT / 4, 256, 0, stream>>>(w, idxw, out);
        vq_pplx<<<1, 1024, 0, stream>>>(counts, out);
    }
}

// Round 7
// 279.637 us; speedup vs baseline: 2.4488x; 2.4488x over previous
//
#include <hip/hip_runtime.h>
#include <math.h>

#define NE   1024
#define ED   256
#define NT   131072
#define SLOTS 32

typedef __attribute__((ext_vector_type(8))) short short8;
typedef __attribute__((ext_vector_type(4))) float f32x4;

__device__ inline unsigned short f2bf(float f) {
    unsigned u = __float_as_uint(f);
    unsigned r = (u + 0x7FFFu + ((u >> 16) & 1u)) >> 16;   // RNE
    return (unsigned short)r;
}

__device__ inline void gl_lds16(const void* g, void* l) {
    __builtin_amdgcn_global_load_lds(
        (const __attribute__((address_space(1))) unsigned int*)g,
        (__attribute__((address_space(3))) unsigned int*)l, 16, 0, 0);
}

// packed candidate: (q(s~) << 16) | code ; q monotone in s~ so u32-min is
// lexicographic (s~, code)-min. q = floor((s + 1024) * 16), clamped.
__device__ inline unsigned pack_cand(float s, int code) {
    float qf = (s + 1024.f) * 16.f;
    int q = (int)qf;
    q = q < 0 ? 0 : (q > 65535 ? 65535 : q);
    return ((unsigned)q << 16) | (unsigned)code;
}

// ---------------------------------------------------------------------------
// ws layout:
//   0        wnorm  f32[1024]
//   4096     counts int[1024]
//   8192     wmax   f32[1]
//   8448     wb     bf16[1024*256]    (512 KB)
//   532736   cnt    u32[131072]       (512 KB)
//   1057024  cand   u32[131072*32]    (16 MB)   need = 17834240
// ---------------------------------------------------------------------------

__global__ __launch_bounds__(256) void vq_prep(const float* __restrict__ w,
                                               float* __restrict__ wnorm,
                                               int* __restrict__ counts,
                                               unsigned short* __restrict__ wb) {
    int c = blockIdx.x * 256 + threadIdx.x;
    if (c < NE) {
        const float4* row = reinterpret_cast<const float4*>(w + (size_t)c * ED);
        ushort4* wbr = reinterpret_cast<ushort4*>(wb + (size_t)c * ED);
        float s = 0.f;
#pragma unroll 8
        for (int i = 0; i < ED / 4; ++i) {
            float4 v = row[i];
            s += v.x * v.x + v.y * v.y + v.z * v.z + v.w * v.w;
            ushort4 o;
            o.x = f2bf(v.x); o.y = f2bf(v.y); o.z = f2bf(v.z); o.w = f2bf(v.w);
            wbr[i] = o;
        }
        wnorm[c] = s;
        counts[c] = 0;
    }
}

__global__ __launch_bounds__(1024) void vq_wmax(const float* __restrict__ wnorm,
                                                float* __restrict__ wmax) {
    __shared__ float red[16];
    int tid = threadIdx.x;
    float v = wnorm[tid];
#pragma unroll
    for (int m = 32; m >= 1; m >>= 1) v = fmaxf(v, __shfl_xor(v, m, 64));
    if ((tid & 63) == 0) red[tid >> 6] = v;
    __syncthreads();
    if (tid == 0) {
        float m = red[0];
#pragma unroll
        for (int i = 1; i < 16; ++i) m = fmaxf(m, red[i]);
        wmax[0] = sqrtf(m);
    }
}

// W-stationary score kernel, swapped MFMA operands: C[row=code][col=token].
// 512 blocks x 512 threads (8 waves x 32 tokens). 4 quarters of 256 codes
// staged once into 128 KB LDS. Epilogue batched over 2 nj-tiles (32 codes):
// token's scores live on 4 l4-lanes -> min-reduce = 2 shuffles, append
// prefix = 3 shuffles. Tight per-batch running min (round-5 cadence).
__global__ __launch_bounds__(512, 2) void vq_score3(const float* __restrict__ z,
                                                    const unsigned short* __restrict__ wb,
                                                    const float* __restrict__ wnorm,
                                                    const float* __restrict__ wmaxp,
                                                    unsigned* __restrict__ cnt,
                                                    unsigned* __restrict__ cand) {
    __shared__ __align__(16) unsigned short wlds[65536];   // 128 KB
    __shared__ float wn_lds[NE];                           // 4 KB
    __shared__ float thr_lds[8][32];                       // 1 KB

    const int tid  = threadIdx.x;
    const int lane = tid & 63;
    const int wv_  = tid >> 6;          // 0..7
    const int l15  = lane & 15;
    const int l4   = lane >> 4;
    const int row0 = blockIdx.x * 256 + wv_ * 32;

    // wnorm -> LDS (512 threads x float2)
    reinterpret_cast<float2*>(wn_lds)[tid] = reinterpret_cast<const float2*>(wnorm)[tid];

    // ---- Z fragments: B-operand layout (col=token=l15, k=kg*32+l4*8+i) ----
    short8 a[2][8];
    float zn2[2];
#pragma unroll
    for (int mi = 0; mi < 2; ++mi) {
        const float* zr = z + (size_t)(row0 + mi * 16 + l15) * ED;
        float s = 0.f;
#pragma unroll
        for (int kg = 0; kg < 8; ++kg) {
            int k0 = kg * 32 + l4 * 8;
            float4 p = *reinterpret_cast<const float4*>(zr + k0);
            float4 q = *reinterpret_cast<const float4*>(zr + k0 + 4);
            s += p.x * p.x + p.y * p.y + p.z * p.z + p.w * p.w
               + q.x * q.x + q.y * q.y + q.z * q.z + q.w * q.w;
            short8 t;
            t[0] = (short)f2bf(p.x); t[1] = (short)f2bf(p.y);
            t[2] = (short)f2bf(p.z); t[3] = (short)f2bf(p.w);
            t[4] = (short)f2bf(q.x); t[5] = (short)f2bf(q.y);
            t[6] = (short)f2bf(q.z); t[7] = (short)f2bf(q.w);
            a[mi][kg] = t;
        }
        zn2[mi] = s;
    }
#pragma unroll
    for (int mi = 0; mi < 2; ++mi) {
        zn2[mi] += __shfl_xor(zn2[mi], 16, 64);
        zn2[mi] += __shfl_xor(zn2[mi], 32, 64);
    }
    float wmax = wmaxp[0];
#pragma unroll
    for (int mi = 0; mi < 2; ++mi)
        thr_lds[wv_][mi * 16 + l15] = 0.0313f * sqrtf(zn2[mi]) * wmax + 0.05f;

    // ---- stage quarter 0: 128 frags of 1 KB; wave wv_ stages s = wv_*16+p ----
#pragma unroll
    for (int p = 0; p < 16; ++p) {
        int s  = wv_ * 16 + p;
        int nj = s >> 3, kg = s & 7;
        int j  = nj * 16 + l15;                          // q = 0
        gl_lds16(wb + (size_t)j * ED + kg * 32 + l4 * 8, &wlds[s * 512]);
    }
    asm volatile("s_waitcnt vmcnt(0) lgkmcnt(0)" ::: "memory");
    __builtin_amdgcn_s_barrier();

    // per-token (token = l15 + 16*mi) threshold / running min / count
    float thrR[2], mn[2];
    int cnt_reg[2];
#pragma unroll
    for (int mi = 0; mi < 2; ++mi) {
        thrR[mi] = thr_lds[wv_][mi * 16 + l15];
        mn[mi] = 3.4e38f;
        cnt_reg[mi] = 0;
    }

    for (int q = 0; q < 4; ++q) {
        const int c0 = q * 256;

        for (int base = 0; base < 16; base += 2) {   // 8 batches of 2 tiles
            f32x4 acc[2][2];   // [tb][mi]
#pragma unroll
            for (int tb = 0; tb < 2; ++tb)
#pragma unroll
                for (int mi = 0; mi < 2; ++mi) acc[tb][mi] = {0.f, 0.f, 0.f, 0.f};

#pragma unroll
            for (int tb = 0; tb < 2; ++tb)
#pragma unroll
                for (int kg = 0; kg < 8; ++kg) {
                    short8 wf = *reinterpret_cast<const short8*>(
                        &wlds[(((base + tb) * 8 + kg) * 512) + lane * 8]);
                    // swapped: A = codes (W), B = tokens (Z)
                    acc[tb][0] = __builtin_amdgcn_mfma_f32_16x16x32_bf16(wf, a[0][kg], acc[tb][0], 0, 0, 0);
                    acc[tb][1] = __builtin_amdgcn_mfma_f32_16x16x32_bf16(wf, a[1][kg], acc[tb][1], 0, 0, 0);
                }

            // wnorm per code: codes of this thread = c0+(base+tb)*16 + l4*4 + r
            float4 wnv[2];
#pragma unroll
            for (int tb = 0; tb < 2; ++tb)
                wnv[tb] = *reinterpret_cast<const float4*>(
                    &wn_lds[c0 + (base + tb) * 16 + l4 * 4]);

            // scores in place; in-thread min per token
            float tmin[2] = {3.4e38f, 3.4e38f};
#pragma unroll
            for (int tb = 0; tb < 2; ++tb)
#pragma unroll
                for (int mi = 0; mi < 2; ++mi) {
                    float wr[4] = {wnv[tb].x, wnv[tb].y, wnv[tb].z, wnv[tb].w};
#pragma unroll
                    for (int r = 0; r < 4; ++r) {
                        float s = fmaf(-2.f, acc[tb][mi][r], wr[r]);
                        acc[tb][mi][r] = s;
                        tmin[mi] = fminf(tmin[mi], s);
                    }
                }
            // cross-l4 reduce (2 shuffles), fold into running min
#pragma unroll
            for (int mi = 0; mi < 2; ++mi) {
                float v = tmin[mi];
                v = fminf(v, __shfl_xor(v, 16, 64));
                v = fminf(v, __shfl_xor(v, 32, 64));
                mn[mi] = fminf(mn[mi], v);
            }

            // keep masks: bit tb*4+r
            unsigned km[2] = {0u, 0u};
#pragma unroll
            for (int tb = 0; tb < 2; ++tb)
#pragma unroll
                for (int mi = 0; mi < 2; ++mi)
#pragma unroll
                    for (int r = 0; r < 4; ++r)
                        if (acc[tb][mi][r] <= mn[mi] + thrR[mi])
                            km[mi] |= 1u << (tb * 4 + r);

            if (__any((km[0] | km[1]) != 0u)) {
#pragma unroll
                for (int mi = 0; mi < 2; ++mi) {
                    int kc = __popc(km[mi]);
                    int b = __shfl_xor(kc, 16, 64);   // l4 ^ 1
                    int c = __shfl_xor(kc, 32, 64);   // l4 ^ 2
                    int d = __shfl_xor(b, 32, 64);    // l4 ^ 3
                    int tot = kc + b + c + d;
                    if (tot > 0) {
                        int pfx = (l4 == 1) ? b
                                : (l4 == 2) ? (c + d)
                                : (l4 == 3) ? (b + c + d) : 0;
                        int tok = row0 + mi * 16 + l15;
                        int o = 0;
#pragma unroll
                        for (int tb = 0; tb < 2; ++tb)
#pragma unroll
                            for (int r = 0; r < 4; ++r)
                                if (km[mi] & (1u << (tb * 4 + r))) {
                                    int pos = cnt_reg[mi] + pfx + o;
                                    if (pos < SLOTS)
                                        cand[(size_t)tok * SLOTS + pos] =
                                            pack_cand(acc[tb][mi][r],
                                                      c0 + (base + tb) * 16 + l4 * 4 + r);
                                    ++o;
                                }
                        cnt_reg[mi] += tot;
                    }
                }
            }
        }

        // re-stage next quarter (single buffer: all waves must be done reading)
        if (q < 3) {
            asm volatile("s_waitcnt lgkmcnt(0)" ::: "memory");
            __builtin_amdgcn_s_barrier();
#pragma unroll
            for (int p = 0; p < 16; ++p) {
                int s  = wv_ * 16 + p;
                int nj = s >> 3, kg = s & 7;
                int j  = (q + 1) * 256 + nj * 16 + l15;
                gl_lds16(wb + (size_t)j * ED + kg * 32 + l4 * 8, &wlds[s * 512]);
            }
            asm volatile("s_waitcnt vmcnt(0) lgkmcnt(0)" ::: "memory");
            __builtin_amdgcn_s_barrier();
        }
    }

    // final per-token candidate counts (4 l4-lanes agree; l4==0 writes)
    if (l4 == 0) {
        cnt[row0 + l15]      = (unsigned)cnt_reg[0];
        cnt[row0 + 16 + l15] = (unsigned)cnt_reg[1];
    }
}

// Exact fp32 refine: wave-parallel prune on packed (q,code), then exact
// evaluation of survivors; fused gather of z_q and counts histogram.
// (round-5 version, proven)
__global__ __launch_bounds__(256) void vq_refine(const float* __restrict__ z,
                                                 const float* __restrict__ w,
                                                 const float* __restrict__ wnorm,
                                                 const float* __restrict__ wmaxp,
                                                 const unsigned* __restrict__ cnt,
                                                 const unsigned* __restrict__ cand,
                                                 int* __restrict__ counts,
                                                 float* __restrict__ out) {
    const int lane = threadIdx.x & 63;
    const int t = blockIdx.x * 4 + (threadIdx.x >> 6);
    float4 zv = reinterpret_cast<const float4*>(z + (size_t)t * ED)[lane];
    unsigned n = cnt[t];
    float bs = 3.4e38f;
    int bj = NE;

    if (n >= 1u && n <= (unsigned)SLOTS) {
        unsigned pk = 0xFFFFFFFFu;
        if (lane < (int)n) pk = cand[(size_t)t * SLOTS + lane];
        unsigned pmin = pk;
#pragma unroll
        for (int m = 1; m < 64; m <<= 1) {
            unsigned o = __shfl_xor(pmin, m, 64);
            pmin = o < pmin ? o : pmin;
        }
        // same thr formula as score; margin covers 2 quantization steps
        float zn = zv.x * zv.x + zv.y * zv.y + zv.z * zv.z + zv.w * zv.w;
#pragma unroll
        for (int m = 1; m < 64; m <<= 1) zn += __shfl_xor(zn, m, 64);
        float thr = 0.0313f * sqrtf(zn) * wmaxp[0] + 0.05f;
        unsigned margin = (unsigned)(16.f * thr) + 2u;
        unsigned qmin = pmin >> 16;
        bool keep = (lane < (int)n) && ((pk >> 16) <= qmin + margin);
        unsigned long long mask = __ballot(keep);
        while (mask) {
            int c = __ffsll(mask) - 1;
            mask &= mask - 1;
            int j = (int)(__shfl(pk, c, 64) & 0xFFFFu);
            float4 wv = reinterpret_cast<const float4*>(w + (size_t)j * ED)[lane];
            float d = fmaf(zv.x, wv.x, fmaf(zv.y, wv.y, fmaf(zv.z, wv.z, zv.w * wv.w)));
#pragma unroll
            for (int m = 1; m < 64; m <<= 1) d += __shfl_xor(d, m, 64);
            float s = fmaf(-2.f, d, wnorm[j]);
            if (s < bs || (s == bs && j < bj)) { bs = s; bj = j; }
        }
    } else {
        // overflow (or impossible empty): exact scan of all codes
        for (int j = 0; j < NE; ++j) {
            float4 wv = reinterpret_cast<const float4*>(w + (size_t)j * ED)[lane];
            float d = fmaf(zv.x, wv.x, fmaf(zv.y, wv.y, fmaf(zv.z, wv.z, zv.w * wv.w)));
#pragma unroll
            for (int m = 1; m < 64; m <<= 1) d += __shfl_xor(d, m, 64);
            float s = fmaf(-2.f, d, wnorm[j]);
            if (s < bs || (s == bs && j < bj)) { bs = s; bj = j; }
        }
    }
    float4 bw = reinterpret_cast<const float4*>(w + (size_t)bj * ED)[lane];
    reinterpret_cast<float4*>(out + (size_t)t * ED)[lane] = bw;
    if (lane == 0) atomicAdd(&counts[bj], 1);
}

__global__ __launch_bounds__(1024) void vq_pplx(const int* __restrict__ counts,
                                                float* __restrict__ out) {
    __shared__ float red[16];
    int tid = threadIdx.x;
    float e = (float)counts[tid] * (1.0f / (float)NT);
    float t = -e * logf(e + 1e-10f);
#pragma unroll
    for (int m = 32; m >= 1; m >>= 1) t += __shfl_down(t, m, 64);
    if ((tid & 63) == 0) red[tid >> 6] = t;
    __syncthreads();
    if (tid < 16) {
        float s = red[tid];
#pragma unroll
        for (int m = 8; m >= 1; m >>= 1) s += __shfl_down(s, m, 16);
        if (tid == 0) out[(size_t)NT * ED] = expf(s);
    }
}

// ======================= fallback (round-1, fp32 VALU) =======================
#define TM 64
#define TN 64
#define KC 64

__global__ __launch_bounds__(256) void vq_prep0(const float* __restrict__ w,
                                                float* __restrict__ wnorm,
                                                int* __restrict__ counts) {
    int c = blockIdx.x * blockDim.x + threadIdx.x;
    if (c < NE) {
        const float4* row = reinterpret_cast<const float4*>(w + (size_t)c * ED);
        float s = 0.f;
#pragma unroll 8
        for (int i = 0; i < ED / 4; ++i) {
            float4 v = row[i];
            s += v.x * v.x + v.y * v.y + v.z * v.z + v.w * v.w;
        }
        wnorm[c] = s;
        counts[c] = 0;
    }
}

__global__ __launch_bounds__(256) void vq_argmin0(const float* __restrict__ z,
                                                  const float* __restrict__ w,
                                                  const float* __restrict__ wnorm,
                                                  int* __restrict__ idx_out,
                                                  int* __restrict__ counts) {
    __shared__ float zs[ED][TM];
    __shared__ float wsh[KC][TN];
    const int tid  = threadIdx.x;
    const int row0 = blockIdx.x * TM;
    const int cg   = tid & 15;
    const int tg   = tid >> 4;
#pragma unroll
    for (int p = 0; p < 16; ++p) {
        int f = p * 256 + tid;
        int k = f >> 4;
        int g = f & 15;
        float4 v;
        v.x = z[(size_t)(row0 + g * 4 + 0) * ED + k];
        v.y = z[(size_t)(row0 + g * 4 + 1) * ED + k];
        v.z = z[(size_t)(row0 + g * 4 + 2) * ED + k];
        v.w = z[(size_t)(row0 + g * 4 + 3) * ED + k];
        *reinterpret_cast<float4*>(&zs[k][g * 4]) = v;
    }
    float best[4];
    int   bidx[4];
#pragma unroll
    for (int i = 0; i < 4; ++i) { best[i] = 3.4e38f; bidx[i] = 0; }
    for (int ct = 0; ct < NE / TN; ++ct) {
        const int c0 = ct * TN;
        float acc[4][4];
#pragma unroll
        for (int i = 0; i < 4; ++i)
#pragma unroll
            for (int j = 0; j < 4; ++j) acc[i][j] = 0.f;
        for (int kc = 0; kc < ED / KC; ++kc) {
            __syncthreads();
#pragma unroll
            for (int p = 0; p < 4; ++p) {
                int f = p * 256 + tid;
                int k = f >> 4;
                int g = f & 15;
                float4 v;
                v.x = w[(size_t)(c0 + g * 4 + 0) * ED + kc * KC + k];
                v.y = w[(size_t)(c0 + g * 4 + 1) * ED + kc * KC + k];
                v.z = w[(size_t)(c0 + g * 4 + 2) * ED + kc * KC + k];
                v.w = w[(size_t)(c0 + g * 4 + 3) * ED + kc * KC + k];
                *reinterpret_cast<float4*>(&wsh[k][g * 4]) = v;
            }
            __syncthreads();
#pragma unroll 8
            for (int k = 0; k < KC; ++k) {
                float4 zv = *reinterpret_cast<const float4*>(&zs[kc * KC + k][tg * 4]);
                float4 wv = *reinterpret_cast<const float4*>(&wsh[k][cg * 4]);
                float zr[4] = { zv.x, zv.y, zv.z, zv.w };
                float wr[4] = { wv.x, wv.y, wv.z, wv.w };
#pragma unroll
                for (int i = 0; i < 4; ++i)
#pragma unroll
                    for (int j = 0; j < 4; ++j)
                        acc[i][j] = fmaf(zr[i], wr[j], acc[i][j]);
            }
        }
#pragma unroll
        for (int j = 0; j < 4; ++j) {
            int c = c0 + cg * 4 + j;
            float wn = wnorm[c];
#pragma unroll
            for (int i = 0; i < 4; ++i) {
                float s = fmaf(-2.f, acc[i][j], wn);
                if (s < best[i]) { best[i] = s; bidx[i] = c; }
            }
        }
    }
#pragma unroll
    for (int m = 1; m < 16; m <<= 1) {
#pragma unroll
        for (int i = 0; i < 4; ++i) {
            float ov = __shfl_xor(best[i], m, 64);
            int   oi = __shfl_xor(bidx[i], m, 64);
            if (ov < best[i] || (ov == best[i] && oi < bidx[i])) {
                best[i] = ov; bidx[i] = oi;
            }
        }
    }
    if (cg == 0) {
#pragma unroll
        for (int i = 0; i < 4; ++i) {
            int t = row0 + tg * 4 + i;
            idx_out[t] = bidx[i];
            atomicAdd(&counts[bidx[i]], 1);
        }
    }
}

__global__ __launch_bounds__(256) void vq_gather0(const float* __restrict__ w,
                                                  const int* __restrict__ idx,
                                                  float* __restrict__ out) {
    int tid = threadIdx.x;
    int t   = blockIdx.x * 4 + (tid >> 6);
    int c4  = tid & 63;
    int id  = idx[t];
    float4 v = reinterpret_cast<const float4*>(w + (size_t)id * ED)[c4];
    reinterpret_cast<float4*>(out + (size_t)t * ED)[c4] = v;
}
// ============================================================================

extern "C" void kernel_launch(void* const* d_in, const int* in_sizes, int n_in,
                              void* d_out, int out_size, void* d_ws, size_t ws_size,
                              hipStream_t stream) {
    const float* z = (const float*)d_in[0];
    const float* w = (const float*)d_in[1];
    float* out = (float*)d_out;
    char* ws = (char*)d_ws;

    float*          wnorm  = (float*)ws;
    int*            counts = (int*)(ws + 4096);
    float*          wmax   = (float*)(ws + 8192);
    unsigned short* wb     = (unsigned short*)(ws + 8448);
    unsigned*       cnt    = (unsigned*)(ws + 532736);
    unsigned*       cand   = (unsigned*)(ws + 1057024);
    const size_t need = 1057024 + (size_t)NT * SLOTS * 4;

    if (ws_size >= need) {
        vq_prep<<<4, 256, 0, stream>>>(w, wnorm, counts, wb);
        vq_wmax<<<1, 1024, 0, stream>>>(wnorm, wmax);
        vq_score3<<<NT / 256, 512, 0, stream>>>(z, wb, wnorm, wmax, cnt, cand);
        vq_refine<<<NT / 4, 256, 0, stream>>>(z, w, wnorm, wmax, cnt, cand, counts, out);
        vq_pplx<<<1, 1024, 0, stream>>>(counts, out);
    } else {
        int* idxw = (int*)(ws + 8192);
        vq_prep0<<<(NE + 255) / 256, 256, 0, stream>>>(w, wnorm, counts);
        vq_argmin0<<<NT / TM, 256, 0, stream>>>(z, w, wnorm, idxw, counts);
        vq_gather0<<<NT / 4, 256, 0, stream>>>(w, idxw, out);
        vq_pplx<<<1, 1024, 0, stream>>>(counts, out);
    }
}